// Round 1
// baseline (118.095 us; speedup 1.0000x reference)
//
#include <hip/hip_runtime.h>
#include <hip/hip_bf16.h>

#define WB 8192
#define WD 128
#define WC 100
#define NSPLIT 16
#define JSPL (WB/NSPLIT)   // 512 j per split
#define JT 32              // j rows per LDS tile
#define NT (JSPL/JT)       // 16 tiles

typedef __attribute__((ext_vector_type(8))) short short8v;
typedef __attribute__((ext_vector_type(4))) float float4v;

#define SCALE_L2 14.426950408889634f  // (1/TAU)/ln2 : sim in log2 units
#define LN2F 0.69314718055994531f

// ---- workspace layout (bytes) ----
#define WS_ZBF   0u          // bf16 z: 8192*128*2 = 2097152
#define WS_S     2097152u    // S[100][128] f32 = 51200
#define WS_SPART 2148352u    // Spart[100][8][128] f32 = 409600
#define WS_CNT   2557952u    // cnt[128] int
#define WS_ACC   2558464u    // accf, accn
#define WS_PART  2558720u    // partials[NSPLIT][8192] float2 = 1048576

__device__ __forceinline__ unsigned short f2bf(float x){
  unsigned u = __float_as_uint(x);
  u += 0x7fffu + ((u>>16)&1u);      // RNE
  return (unsigned short)(u>>16);
}

__global__ __launch_bounds__(256) void k_prep(const float* __restrict__ z,
                                              unsigned short* __restrict__ zbf){
  int idx = blockIdx.x*256 + threadIdx.x;     // 131072 threads, 8 elems each
  const float4* zi = (const float4*)z;
  float4 a = zi[idx*2], b = zi[idx*2+1];
  uint4 o;
  o.x = (unsigned)f2bf(a.x) | ((unsigned)f2bf(a.y)<<16);
  o.y = (unsigned)f2bf(a.z) | ((unsigned)f2bf(a.w)<<16);
  o.z = (unsigned)f2bf(b.x) | ((unsigned)f2bf(b.y)<<16);
  o.w = (unsigned)f2bf(b.z) | ((unsigned)f2bf(b.w)<<16);
  ((uint4*)zbf)[idx] = o;
}

__global__ void k_zero(float* accf, int* accn, int* cnt){
  int t = threadIdx.x;
  if (t < 128) cnt[t] = 0;
  if (t == 0){ accf[0] = 0.f; accn[0] = 0; }
}

// class partial sums: grid (100 classes, 8 chunks) x 128 threads (one col each)
__global__ __launch_bounds__(128) void k_cpart(const float* __restrict__ z,
                                               const int* __restrict__ labels,
                                               float* __restrict__ Spart,
                                               int* __restrict__ cnt){
  __shared__ int labs[1024];
  int c = blockIdx.x, ch = blockIdx.y;
  int base = ch*1024;
  for (int t = threadIdx.x; t < 1024; t += 128) labs[t] = labels[base+t];
  __syncthreads();
  int col = threadIdx.x;
  float acc = 0.f; int count = 0;
  for (int i = 0; i < 1024; i++){
    if (labs[i] == c){ acc += z[(size_t)(base+i)*WD + col]; count++; }
  }
  Spart[(size_t)(c*8+ch)*WD + col] = acc;
  if (col == 0) atomicAdd(&cnt[c], count);
}

__global__ __launch_bounds__(256) void k_sred(const float* __restrict__ Spart,
                                              float* __restrict__ S){
  int idx = blockIdx.x*256 + threadIdx.x;
  if (idx >= WC*WD) return;
  int c = idx / WD, col = idx % WD;
  float s = 0.f;
  for (int ch = 0; ch < 8; ch++) s += Spart[(size_t)(c*8+ch)*WD + col];
  S[idx] = s;
}

// main LSE kernel: grid (32 anchor-blocks, NSPLIT) x 256 threads (4 waves)
// wave owns 64 anchors (4 sets of 16); streams j tiles of 32 via LDS.
__global__ __launch_bounds__(256) void k_lse(const unsigned short* __restrict__ zbf,
                                             float2* __restrict__ part){
  __shared__ unsigned char lds[2][JT*256];   // 2 x 8 KB, row stride 256 B
  const int t = threadIdx.x;
  const int wv = t>>6, lane = t&63;
  const int awave = blockIdx.x*256 + wv*64;
  const int split = blockIdx.y;
  const int j0 = split*JSPL;
  const int lg = lane>>4, ln = lane&15;

  // anchor B-fragments: B[k][n] = z[awave+ss*16+n][k]; lane: n=ln, k=kk*32+lg*8+e
  short8v bf[4][4];
  #pragma unroll
  for (int ss = 0; ss < 4; ss++){
    const unsigned short* zr = zbf + (size_t)(awave + ss*16 + ln)*WD;
    #pragma unroll
    for (int kk = 0; kk < 4; kk++)
      bf[ss][kk] = *(const short8v*)(zr + kk*32 + lg*8);
  }

  float m[4], l[4];
  #pragma unroll
  for (int ss = 0; ss < 4; ss++){ m[ss] = -INFINITY; l[ss] = 0.f; }

  // stage tile 0 (each thread: 2 x 16B chunks, XOR-swizzled LDS write)
  {
    int cid = t*2, row = cid>>4, ck = cid&15;
    uint4 v0 = *(const uint4*)(zbf + (size_t)(j0+row)*WD + ck*8);
    uint4 v1 = *(const uint4*)(zbf + (size_t)(j0+row)*WD + (ck+1)*8);
    *(uint4*)&lds[0][row*256 + ((ck*16)     ^ ((row&7)<<4))] = v0;
    *(uint4*)&lds[0][row*256 + (((ck+1)*16) ^ ((row&7)<<4))] = v1;
  }
  __syncthreads();

  for (int tt = 0; tt < NT; tt++){
    const int bufc = tt & 1;
    uint4 p0 = {0,0,0,0}, p1 = {0,0,0,0};
    int prow = 0, pck = 0;
    if (tt+1 < NT){           // issue next-tile global loads early
      int jt = j0 + (tt+1)*JT;
      int cid = t*2; prow = cid>>4; pck = cid&15;
      p0 = *(const uint4*)(zbf + (size_t)(jt+prow)*WD + pck*8);
      p1 = *(const uint4*)(zbf + (size_t)(jt+prow)*WD + (pck+1)*8);
    }
    #pragma unroll
    for (int s = 0; s < 2; s++){
      const int rl = s*16 + ln;
      const int jb = j0 + tt*JT + s*16;
      short8v af[4];
      #pragma unroll
      for (int kk = 0; kk < 4; kk++)
        af[kk] = *(const short8v*)&lds[bufc][rl*256 + ((kk*64 + lg*16) ^ ((rl&7)<<4))];
      #pragma unroll
      for (int ss = 0; ss < 4; ss++){
        float4v acc = {0.f,0.f,0.f,0.f};
        #pragma unroll
        for (int kk = 0; kk < 4; kk++)
          acc = __builtin_amdgcn_mfma_f32_16x16x32_bf16(af[kk], bf[ss][kk], acc, 0,0,0);
        // C[row=j, col=anchor]: j = jb + lg*4 + reg, anchor = awave+ss*16+ln
        float v0 = acc[0]*SCALE_L2, v1 = acc[1]*SCALE_L2,
              v2 = acc[2]*SCALE_L2, v3 = acc[3]*SCALE_L2;
        if (jb == awave + ss*16){        // diagonal tile: mask self
          int r0 = lg*4;
          if (r0+0 == ln) v0 = -INFINITY;
          if (r0+1 == ln) v1 = -INFINITY;
          if (r0+2 == ln) v2 = -INFINITY;
          if (r0+3 == ln) v3 = -INFINITY;
        }
        float tmax = fmaxf(fmaxf(v0,v1), fmaxf(v2,v3));
        float mn = fmaxf(m[ss], tmax);
        l[ss] = l[ss]*exp2f(m[ss]-mn)
              + exp2f(v0-mn) + exp2f(v1-mn) + exp2f(v2-mn) + exp2f(v3-mn);
        m[ss] = mn;
      }
    }
    if (tt+1 < NT){           // write staged tile into other buffer
      *(uint4*)&lds[bufc^1][prow*256 + ((pck*16)     ^ ((prow&7)<<4))] = p0;
      *(uint4*)&lds[bufc^1][prow*256 + (((pck+1)*16) ^ ((prow&7)<<4))] = p1;
    }
    __syncthreads();
  }

  // combine lanes {x, x^16, x^32, x^48} (same anchor) and write split partials
  #pragma unroll
  for (int ss = 0; ss < 4; ss++){
    float mm = m[ss], ll = l[ss];
    #pragma unroll
    for (int off = 16; off < 64; off <<= 1){
      float mo = __shfl_xor(mm, off);
      float lo = __shfl_xor(ll, off);
      float M = fmaxf(mm, mo);
      ll = ll*exp2f(mm-M) + lo*exp2f(mo-M);
      mm = M;
    }
    if (lane < 16)
      part[(size_t)split*WB + awave + ss*16 + lane] = make_float2(mm, ll);
  }
}

__global__ __launch_bounds__(256) void k_final(const float* __restrict__ z,
                                               const int* __restrict__ labels,
                                               const float* __restrict__ S,
                                               const int* __restrict__ cnt,
                                               const float2* __restrict__ part,
                                               float* __restrict__ accf,
                                               int* __restrict__ accn){
  int i = blockIdx.x*256 + threadIdx.x;
  float mm = -INFINITY, ll = 0.f;
  for (int sp = 0; sp < NSPLIT; sp++){
    float2 p = part[(size_t)sp*WB + i];
    float M = fmaxf(mm, p.x);
    ll = ll*exp2f(mm-M) + p.y*exp2f(p.x-M);
    mm = M;
  }
  float lse = (mm + log2f(ll)) * LN2F;          // natural-log LSE
  int lab = labels[i];
  const float4* zi = (const float4*)(z + (size_t)i*WD);
  const float4* sc = (const float4*)(S + (size_t)lab*WD);
  float pd = 0.f, sd = 0.f;
  #pragma unroll 8
  for (int k = 0; k < WD/4; k++){
    float4 a = zi[k], b = sc[k];
    pd += a.x*b.x + a.y*b.y + a.z*b.z + a.w*b.w;
    sd += a.x*a.x + a.y*a.y + a.z*a.z + a.w*a.w;
  }
  int np = cnt[lab] - 1;
  float loss = 0.f, val = 0.f;
  if (np > 0){ loss = lse - (pd - sd)*10.0f/(float)np; val = 1.f; }
  #pragma unroll
  for (int off = 32; off > 0; off >>= 1){
    loss += __shfl_down(loss, off);
    val  += __shfl_down(val,  off);
  }
  __shared__ float sl[4], sv[4];
  int wv = threadIdx.x>>6, lane = threadIdx.x&63;
  if (lane == 0){ sl[wv] = loss; sv[wv] = val; }
  __syncthreads();
  if (threadIdx.x == 0){
    atomicAdd(accf, sl[0]+sl[1]+sl[2]+sl[3]);
    atomicAdd(accn, (int)(sv[0]+sv[1]+sv[2]+sv[3] + 0.5f));
  }
}

__global__ void k_out(const float* accf, const int* accn, float* out){
  out[0] = accf[0] / (float)max(accn[0], 1);
}

extern "C" void kernel_launch(void* const* d_in, const int* in_sizes, int n_in,
                              void* d_out, int out_size, void* d_ws, size_t ws_size,
                              hipStream_t stream){
  const float* z = (const float*)d_in[0];
  const int* labels = (const int*)d_in[1];
  char* ws = (char*)d_ws;
  unsigned short* zbf = (unsigned short*)(ws + WS_ZBF);
  float* S     = (float*)(ws + WS_S);
  float* Spart = (float*)(ws + WS_SPART);
  int*   cnt   = (int*)(ws + WS_CNT);
  float* accf  = (float*)(ws + WS_ACC);
  int*   accn  = (int*)(ws + WS_ACC + 4);
  float2* part = (float2*)(ws + WS_PART);
  float* out = (float*)d_out;

  hipLaunchKernelGGL(k_prep,  dim3(512),        dim3(256), 0, stream, z, zbf);
  hipLaunchKernelGGL(k_zero,  dim3(1),          dim3(256), 0, stream, accf, accn, cnt);
  hipLaunchKernelGGL(k_cpart, dim3(WC, 8),      dim3(128), 0, stream, z, labels, Spart, cnt);
  hipLaunchKernelGGL(k_sred,  dim3(50),         dim3(256), 0, stream, Spart, S);
  hipLaunchKernelGGL(k_lse,   dim3(WB/256, NSPLIT), dim3(256), 0, stream, zbf, part);
  hipLaunchKernelGGL(k_final, dim3(WB/256),     dim3(256), 0, stream, z, labels, S, cnt, part, accf, accn);
  hipLaunchKernelGGL(k_out,   dim3(1),          dim3(1),   0, stream, accf, accn, out);
}

// Round 2
// 76.883 us; speedup vs baseline: 1.5360x; 1.5360x over previous
//
#include <hip/hip_runtime.h>
#include <hip/hip_bf16.h>

#define WB 8192
#define WD 128
#define WC 100
#define NSPLIT 16
#define JSPL (WB/NSPLIT)   // 512 j per split
#define JT 32              // j rows per LDS tile
#define NT (JSPL/JT)       // 16 tiles

typedef __attribute__((ext_vector_type(8))) short short8v;
typedef __attribute__((ext_vector_type(4))) float float4v;

#define SCALE_L2 14.426950408889634f  // (1/TAU)/ln2 : sim in log2 units
#define LN2F 0.69314718055994531f

// ---- workspace layout (bytes) ----
#define WS_ZBF   0u          // bf16 z: 8192*128*2 = 2097152
#define WS_S     2097152u    // S[100][128] f32 = 51200
#define WS_CNT   2148352u    // cnt[128] int
#define WS_ACC   2148864u    // accf, accn
#define WS_PART  2149120u    // partials[NSPLIT][8192] float2 = 1048576

__device__ __forceinline__ unsigned short f2bf(float x){
  unsigned u = __float_as_uint(x);
  u += 0x7fffu + ((u>>16)&1u);      // RNE
  return (unsigned short)(u>>16);
}

__global__ __launch_bounds__(256) void k_prep(const float* __restrict__ z,
                                              unsigned short* __restrict__ zbf){
  int idx = blockIdx.x*256 + threadIdx.x;     // 131072 threads, 8 elems each
  const float4* zi = (const float4*)z;
  float4 a = zi[idx*2], b = zi[idx*2+1];
  uint4 o;
  o.x = (unsigned)f2bf(a.x) | ((unsigned)f2bf(a.y)<<16);
  o.y = (unsigned)f2bf(a.z) | ((unsigned)f2bf(a.w)<<16);
  o.z = (unsigned)f2bf(b.x) | ((unsigned)f2bf(b.y)<<16);
  o.w = (unsigned)f2bf(b.z) | ((unsigned)f2bf(b.w)<<16);
  ((uint4*)zbf)[idx] = o;
}

// zero S, cnt, acc
__global__ __launch_bounds__(256) void k_zero(float* S, float* accf, int* accn, int* cnt){
  int idx = blockIdx.x*256 + threadIdx.x;
  if (idx < WC*WD) S[idx] = 0.f;
  if (blockIdx.x == 0){
    int t = threadIdx.x;
    if (t < 128) cnt[t] = 0;
    if (t == 0){ accf[0] = 0.f; accn[0] = 0; }
  }
}

// class sums via LDS histogram: grid (64 row-chunks, 2 col-halves) x 256
// block owns rows [bx*128, +128), cols [by*64, +64); acc[100][64] in LDS.
__global__ __launch_bounds__(256) void k_csum(const float* __restrict__ z,
                                              const int* __restrict__ labels,
                                              float* __restrict__ S,
                                              int* __restrict__ cnt){
  __shared__ float sacc[WC*64];
  __shared__ int slcnt[WC];
  const int t = threadIdx.x;
  const int rowBase = blockIdx.x*128;
  const int colBase = blockIdx.y*64;
  for (int i = t; i < WC*64; i += 256) sacc[i] = 0.f;
  if (t < WC) slcnt[t] = 0;
  __syncthreads();

  const int col = t & 63;          // 0..63 within half
  const int rsub = t >> 6;         // 4 rows per iteration
  #pragma unroll 4
  for (int r0 = 0; r0 < 128; r0 += 4){
    int row = rowBase + r0 + rsub;
    int lab = labels[row];
    float v = z[(size_t)row*WD + colBase + col];
    atomicAdd(&sacc[lab*64 + col], v);
    if (col == 0 && blockIdx.y == 0) atomicAdd(&slcnt[lab], 1);
  }
  __syncthreads();

  for (int i = t; i < WC*64; i += 256){
    float v = sacc[i];
    if (v != 0.f) atomicAdd(&S[(i>>6)*WD + colBase + (i&63)], v);
  }
  if (blockIdx.y == 0 && t < WC && slcnt[t] > 0) atomicAdd(&cnt[t], slcnt[t]);
}

// main LSE kernel: grid (32 anchor-blocks, NSPLIT) x 256 threads (4 waves)
// wave owns 64 anchors (4 sets of 16); streams j tiles of 32 via LDS.
__global__ __launch_bounds__(256) void k_lse(const unsigned short* __restrict__ zbf,
                                             float2* __restrict__ part){
  __shared__ unsigned char lds[2][JT*256];   // 2 x 8 KB, row stride 256 B
  const int t = threadIdx.x;
  const int wv = t>>6, lane = t&63;
  const int awave = blockIdx.x*256 + wv*64;
  const int split = blockIdx.y;
  const int j0 = split*JSPL;
  const int lg = lane>>4, ln = lane&15;

  // anchor B-fragments: B[k][n] = z[awave+ss*16+n][k]; lane: n=ln, k=kk*32+lg*8+e
  short8v bf[4][4];
  #pragma unroll
  for (int ss = 0; ss < 4; ss++){
    const unsigned short* zr = zbf + (size_t)(awave + ss*16 + ln)*WD;
    #pragma unroll
    for (int kk = 0; kk < 4; kk++)
      bf[ss][kk] = *(const short8v*)(zr + kk*32 + lg*8);
  }

  float m[4], l[4];
  #pragma unroll
  for (int ss = 0; ss < 4; ss++){ m[ss] = -INFINITY; l[ss] = 0.f; }

  // stage tile 0 (each thread: 2 x 16B chunks, XOR-swizzled LDS write)
  {
    int cid = t*2, row = cid>>4, ck = cid&15;
    uint4 v0 = *(const uint4*)(zbf + (size_t)(j0+row)*WD + ck*8);
    uint4 v1 = *(const uint4*)(zbf + (size_t)(j0+row)*WD + (ck+1)*8);
    *(uint4*)&lds[0][row*256 + ((ck*16)     ^ ((row&7)<<4))] = v0;
    *(uint4*)&lds[0][row*256 + (((ck+1)*16) ^ ((row&7)<<4))] = v1;
  }
  __syncthreads();

  for (int tt = 0; tt < NT; tt++){
    const int bufc = tt & 1;
    uint4 p0 = {0,0,0,0}, p1 = {0,0,0,0};
    int prow = 0, pck = 0;
    if (tt+1 < NT){           // issue next-tile global loads early
      int jt = j0 + (tt+1)*JT;
      int cid = t*2; prow = cid>>4; pck = cid&15;
      p0 = *(const uint4*)(zbf + (size_t)(jt+prow)*WD + pck*8);
      p1 = *(const uint4*)(zbf + (size_t)(jt+prow)*WD + (pck+1)*8);
    }
    #pragma unroll
    for (int s = 0; s < 2; s++){
      const int rl = s*16 + ln;
      const int jb = j0 + tt*JT + s*16;
      short8v af[4];
      #pragma unroll
      for (int kk = 0; kk < 4; kk++)
        af[kk] = *(const short8v*)&lds[bufc][rl*256 + ((kk*64 + lg*16) ^ ((rl&7)<<4))];
      #pragma unroll
      for (int ss = 0; ss < 4; ss++){
        float4v acc = {0.f,0.f,0.f,0.f};
        #pragma unroll
        for (int kk = 0; kk < 4; kk++)
          acc = __builtin_amdgcn_mfma_f32_16x16x32_bf16(af[kk], bf[ss][kk], acc, 0,0,0);
        // C[row=j, col=anchor]: j = jb + lg*4 + reg, anchor = awave+ss*16+ln
        float v0 = acc[0]*SCALE_L2, v1 = acc[1]*SCALE_L2,
              v2 = acc[2]*SCALE_L2, v3 = acc[3]*SCALE_L2;
        if (jb == awave + ss*16){        // diagonal tile: mask self
          int r0 = lg*4;
          if (r0+0 == ln) v0 = -INFINITY;
          if (r0+1 == ln) v1 = -INFINITY;
          if (r0+2 == ln) v2 = -INFINITY;
          if (r0+3 == ln) v3 = -INFINITY;
        }
        float tmax = fmaxf(fmaxf(v0,v1), fmaxf(v2,v3));
        float mn = fmaxf(m[ss], tmax);
        l[ss] = l[ss]*exp2f(m[ss]-mn)
              + exp2f(v0-mn) + exp2f(v1-mn) + exp2f(v2-mn) + exp2f(v3-mn);
        m[ss] = mn;
      }
    }
    if (tt+1 < NT){           // write staged tile into other buffer
      *(uint4*)&lds[bufc^1][prow*256 + ((pck*16)     ^ ((prow&7)<<4))] = p0;
      *(uint4*)&lds[bufc^1][prow*256 + (((pck+1)*16) ^ ((prow&7)<<4))] = p1;
    }
    __syncthreads();
  }

  // combine lanes {x, x^16, x^32, x^48} (same anchor) and write split partials
  #pragma unroll
  for (int ss = 0; ss < 4; ss++){
    float mm = m[ss], ll = l[ss];
    #pragma unroll
    for (int off = 16; off < 64; off <<= 1){
      float mo = __shfl_xor(mm, off);
      float lo = __shfl_xor(ll, off);
      float M = fmaxf(mm, mo);
      ll = ll*exp2f(mm-M) + lo*exp2f(mo-M);
      mm = M;
    }
    if (lane < 16)
      part[(size_t)split*WB + awave + ss*16 + lane] = make_float2(mm, ll);
  }
}

__global__ __launch_bounds__(256) void k_final(const float* __restrict__ z,
                                               const int* __restrict__ labels,
                                               const float* __restrict__ S,
                                               const int* __restrict__ cnt,
                                               const float2* __restrict__ part,
                                               float* __restrict__ accf,
                                               int* __restrict__ accn){
  int i = blockIdx.x*256 + threadIdx.x;
  float mm = -INFINITY, ll = 0.f;
  for (int sp = 0; sp < NSPLIT; sp++){
    float2 p = part[(size_t)sp*WB + i];
    float M = fmaxf(mm, p.x);
    ll = ll*exp2f(mm-M) + p.y*exp2f(p.x-M);
    mm = M;
  }
  float lse = (mm + log2f(ll)) * LN2F;          // natural-log LSE
  int lab = labels[i];
  const float4* zi = (const float4*)(z + (size_t)i*WD);
  const float4* sc = (const float4*)(S + (size_t)lab*WD);
  float pd = 0.f, sd = 0.f;
  #pragma unroll 8
  for (int k = 0; k < WD/4; k++){
    float4 a = zi[k], b = sc[k];
    pd += a.x*b.x + a.y*b.y + a.z*b.z + a.w*b.w;
    sd += a.x*a.x + a.y*a.y + a.z*a.z + a.w*a.w;
  }
  int np = cnt[lab] - 1;
  float loss = 0.f, val = 0.f;
  if (np > 0){ loss = lse - (pd - sd)*10.0f/(float)np; val = 1.f; }
  #pragma unroll
  for (int off = 32; off > 0; off >>= 1){
    loss += __shfl_down(loss, off);
    val  += __shfl_down(val,  off);
  }
  __shared__ float sl[4], sv[4];
  int wv = threadIdx.x>>6, lane = threadIdx.x&63;
  if (lane == 0){ sl[wv] = loss; sv[wv] = val; }
  __syncthreads();
  if (threadIdx.x == 0){
    atomicAdd(accf, sl[0]+sl[1]+sl[2]+sl[3]);
    atomicAdd(accn, (int)(sv[0]+sv[1]+sv[2]+sv[3] + 0.5f));
  }
}

__global__ void k_out(const float* accf, const int* accn, float* out){
  out[0] = accf[0] / (float)max(accn[0], 1);
}

extern "C" void kernel_launch(void* const* d_in, const int* in_sizes, int n_in,
                              void* d_out, int out_size, void* d_ws, size_t ws_size,
                              hipStream_t stream){
  const float* z = (const float*)d_in[0];
  const int* labels = (const int*)d_in[1];
  char* ws = (char*)d_ws;
  unsigned short* zbf = (unsigned short*)(ws + WS_ZBF);
  float* S     = (float*)(ws + WS_S);
  int*   cnt   = (int*)(ws + WS_CNT);
  float* accf  = (float*)(ws + WS_ACC);
  int*   accn  = (int*)(ws + WS_ACC + 4);
  float2* part = (float2*)(ws + WS_PART);
  float* out = (float*)d_out;

  hipLaunchKernelGGL(k_prep,  dim3(512),            dim3(256), 0, stream, z, zbf);
  hipLaunchKernelGGL(k_zero,  dim3(51),             dim3(256), 0, stream, S, accf, accn, cnt);
  hipLaunchKernelGGL(k_csum,  dim3(64, 2),          dim3(256), 0, stream, z, labels, S, cnt);
  hipLaunchKernelGGL(k_lse,   dim3(WB/256, NSPLIT), dim3(256), 0, stream, zbf, part);
  hipLaunchKernelGGL(k_final, dim3(WB/256),         dim3(256), 0, stream, z, labels, S, cnt, part, accf, accn);
  hipLaunchKernelGGL(k_out,   dim3(1),              dim3(1),   0, stream, accf, accn, out);
}